// Round 4
// baseline (329.950 us; speedup 1.0000x reference)
//
#include <hip/hip_runtime.h>
#include <math.h>

#define NB 8
#define CC 512
#define HH 64
#define WW 64
#define GG 16
#define GCH 32
#define OO 32   // 2*G offset rows
#define NGHW (NB * GG * HH * WW)   // 524288 elements per coord buffer

__device__ __forceinline__ float gelu_exact(float x) {
    return 0.5f * x * (1.0f + erff(x * 0.70710678118654752f));
}

// ============================================================================
// Kernel A: dwconv3x3 + LayerNorm + GELU + offset matvec -> px/py buffers
// grid (HH, NB), block 512.
// CRITICAL: every loop touching xv[][] is FULLY unrolled. Round-3's
// `#pragma unroll 4` left runtime indices -> xv lived in scratch -> 132 MB
// of spill writes per dispatch (the whole bottleneck).
// ============================================================================
__global__ __launch_bounds__(512, 2)
void offsets_kernel(const float* __restrict__ in_first,
                    const float* __restrict__ dw_w,
                    const float* __restrict__ dw_b,
                    const float* __restrict__ ln_g,
                    const float* __restrict__ ln_b,
                    const float* __restrict__ off_w,
                    const float* __restrict__ off_b,
                    float* __restrict__ coord_ws)
{
    const int h   = blockIdx.x;   // 0..63
    const int n   = blockIdx.y;   // 0..7
    const int tid = threadIdx.x;  // 0..511
    const int wq   = tid & 15;    // 16 quads of w
    const int cgrp = tid >> 4;    // 32 groups of 16 channels
    const int wb = wq * 4;
    const int c0 = cgrp * 16;

    __shared__ float redS [64 * 33];
    __shared__ float redS2[64 * 33];
    __shared__ float meanArr[64];
    __shared__ float rstdArr[64];
    __shared__ float offacc[64 * 33];   // [w][o]

    float xv[4][16];                    // MUST stay in VGPRs (64 regs)
    float sw [4] = {0.f, 0.f, 0.f, 0.f};
    float sw2[4] = {0.f, 0.f, 0.f, 0.f};

    // ---------- Phase A: depthwise 3x3 conv + bias ----------
    // halo (left/right) via shfl from the neighbor lane's float4.
    #pragma unroll
    for (int i = 0; i < 16; ++i) {
        const int c = c0 + i;
        float w9[9];
        #pragma unroll
        for (int k = 0; k < 9; ++k) w9[k] = dw_w[c * 9 + k];
        const float b = dw_b[c];
        float a0 = b, a1 = b, a2 = b, a3 = b;
        #pragma unroll
        for (int r = 0; r < 3; ++r) {
            const int y = h + r - 1;
            if (y < 0 || y >= HH) continue;
            const float* rowp = in_first + ((n * CC + c) * HH + y) * WW;
            const float4 m = *(const float4*)(rowp + wb);
            float left  = __shfl_up(m.w, 1);
            float right = __shfl_down(m.x, 1);
            if (wq == 0)  left  = 0.0f;
            if (wq == 15) right = 0.0f;
            const float k0 = w9[r * 3 + 0], k1 = w9[r * 3 + 1], k2 = w9[r * 3 + 2];
            a0 += k0 * left + k1 * m.x + k2 * m.y;
            a1 += k0 * m.x  + k1 * m.y + k2 * m.z;
            a2 += k0 * m.y  + k1 * m.z + k2 * m.w;
            a3 += k0 * m.z  + k1 * m.w + k2 * right;
        }
        xv[0][i] = a0; xv[1][i] = a1; xv[2][i] = a2; xv[3][i] = a3;
        sw[0] += a0; sw2[0] += a0 * a0;
        sw[1] += a1; sw2[1] += a1 * a1;
        sw[2] += a2; sw2[2] += a2 * a2;
        sw[3] += a3; sw2[3] += a3 * a3;
    }

    // ---------- Phase B: LayerNorm stats over C per pixel ----------
    #pragma unroll
    for (int j = 0; j < 4; ++j) {
        redS [(wb + j) * 33 + cgrp] = sw[j];
        redS2[(wb + j) * 33 + cgrp] = sw2[j];
    }
    __syncthreads();
    if (tid < 64) {
        const int w = tid;
        float s = 0.f, s2 = 0.f;
        for (int k = 0; k < 32; ++k) {
            s  += redS [w * 33 + k];
            s2 += redS2[w * 33 + k];
        }
        const float mu  = s * (1.0f / 512.0f);
        const float var = s2 * (1.0f / 512.0f) - mu * mu;
        meanArr[w] = mu;
        rstdArr[w] = rsqrtf(var + 1e-6f);
    }
    __syncthreads();
    for (int idx = tid; idx < 64 * 32; idx += 512) {
        offacc[(idx >> 5) * 33 + (idx & 31)] = 0.0f;
    }

    // ---------- Phase C: LN affine + exact GELU (in registers) ----------
    float mu_[4], rs_[4];
    #pragma unroll
    for (int j = 0; j < 4; ++j) { mu_[j] = meanArr[wb + j]; rs_[j] = rstdArr[wb + j]; }
    #pragma unroll
    for (int i = 0; i < 16; ++i) {
        const int c = c0 + i;
        const float lg = ln_g[c];
        const float lb = ln_b[c];
        #pragma unroll
        for (int j = 0; j < 4; ++j) {
            const float v = (xv[j][i] - mu_[j]) * rs_[j] * lg + lb;
            xv[j][i] = gelu_exact(v);
        }
    }
    __syncthreads();   // offacc zeroed + x1 ready

    // ---------- Phase D: offset matvec ----------
    // In-wave pre-reduction over the 4 cgrp lanes sharing each wq, then one
    // LDS atomic per 16 lanes.
    const int lane = tid & 63;
    for (int o = 0; o < OO; ++o) {
        const float4* wp = (const float4*)(off_w + o * CC + c0);
        const float4 w0 = wp[0], w1 = wp[1], w2 = wp[2], w3 = wp[3];
        #pragma unroll
        for (int j = 0; j < 4; ++j) {
            float f = w0.x * xv[j][0]  + w0.y * xv[j][1]  + w0.z * xv[j][2]  + w0.w * xv[j][3]
                    + w1.x * xv[j][4]  + w1.y * xv[j][5]  + w1.z * xv[j][6]  + w1.w * xv[j][7]
                    + w2.x * xv[j][8]  + w2.y * xv[j][9]  + w2.z * xv[j][10] + w2.w * xv[j][11]
                    + w3.x * xv[j][12] + w3.y * xv[j][13] + w3.z * xv[j][14] + w3.w * xv[j][15];
            f += __shfl_down(f, 32);
            f += __shfl_down(f, 16);
            if (lane < 16)
                atomicAdd(&offacc[(wb + j) * 33 + o], f);
        }
    }
    __syncthreads();

    // ---------- Phase E: emit absolute sample coords px/py ----------
    {
        const int o   = tid & 31;
        const int wg4 = (tid >> 5) * 4;
        const int g   = o >> 1;
        const float ob = off_b[o];
        float* dst = coord_ws + (size_t)(o & 1) * NGHW
                   + (((size_t)n * GG + g) * HH + h) * WW;
        #pragma unroll
        for (int j = 0; j < 4; ++j) {
            const int w = wg4 + j;
            const float wbase = (o & 1) ? (float)h : (float)w;
            dst[w] = wbase + offacc[w * 33 + o] + ob;
        }
    }
}

// ============================================================================
// Kernel B: bilinear gather + LDS transpose + coalesced NCHW store.
// grid (HH, NB, GG), block 256.
// ============================================================================
__global__ __launch_bounds__(256)
void sample_kernel(const float* __restrict__ in_last,
                   const float* __restrict__ coord_ws,
                   float* __restrict__ out)
{
    const int h   = blockIdx.x;
    const int n   = blockIdx.y;
    const int g   = blockIdx.z;
    const int tid = threadIdx.x;

    __shared__ float pxs[64];
    __shared__ float pys[64];
    __shared__ float smem[64 * 33];   // [w][c], stride 33

    if (tid < 128) {
        const int w = tid & 63;
        const size_t cidx = (((size_t)n * GG + g) * HH + h) * WW + w;
        if (tid < 64) pxs[w] = coord_ws[cidx];
        else          pys[w] = coord_ws[cidx + NGHW];
    }
    __syncthreads();

    const int c4    = tid & 7;
    const int wslot = tid >> 3;
    const float* base = in_last + (size_t)n * HH * WW * CC + g * GCH + c4 * 4;

    #pragma unroll
    for (int pass = 0; pass < 2; ++pass) {
        const int w = wslot + pass * 32;
        const float px = pxs[w];
        const float py = pys[w];
        const float x0f = floorf(px), y0f = floorf(py);
        const float fx = px - x0f, fy = py - y0f;
        const int x0 = (int)x0f, y0 = (int)y0f;

        float4 acc = make_float4(0.f, 0.f, 0.f, 0.f);
        #pragma unroll
        for (int t = 0; t < 4; ++t) {
            const int xi = x0 + (t & 1);
            const int yi = y0 + (t >> 1);
            const float wt = ((t & 1) ? fx : 1.0f - fx) * ((t >> 1) ? fy : 1.0f - fy);
            if (xi >= 0 && xi < WW && yi >= 0 && yi < HH) {
                const float4 v = *(const float4*)(base + ((size_t)yi * WW + xi) * CC);
                acc.x += wt * v.x;
                acc.y += wt * v.y;
                acc.z += wt * v.z;
                acc.w += wt * v.w;
            }
        }
        float* sp = smem + w * 33 + c4 * 4;
        sp[0] = acc.x; sp[1] = acc.y; sp[2] = acc.z; sp[3] = acc.w;
    }
    __syncthreads();

    const int w  = tid & 63;
    const int cb = tid >> 6;
    float* op = out + (((size_t)n * CC + g * GCH) * HH + h) * WW + w;
    #pragma unroll
    for (int pass = 0; pass < 8; ++pass) {
        const int c = pass * 4 + cb;
        op[(size_t)c * (HH * WW)] = smem[w * 33 + c];
    }
}

extern "C" void kernel_launch(void* const* d_in, const int* in_sizes, int n_in,
                              void* d_out, int out_size, void* d_ws, size_t ws_size,
                              hipStream_t stream) {
    const float* in_first = (const float*)d_in[0];
    const float* in_last  = (const float*)d_in[1];
    const float* dw_w     = (const float*)d_in[2];
    const float* dw_b     = (const float*)d_in[3];
    const float* ln_g     = (const float*)d_in[4];
    const float* ln_b     = (const float*)d_in[5];
    const float* off_w    = (const float*)d_in[6];
    const float* off_b    = (const float*)d_in[7];
    float* out      = (float*)d_out;
    float* coord_ws = (float*)d_ws;   // 2*NGHW*4 = 4 MiB

    dim3 gridA(HH, NB);
    offsets_kernel<<<gridA, 512, 0, stream>>>(in_first, dw_w, dw_b, ln_g, ln_b,
                                              off_w, off_b, coord_ws);

    dim3 gridB(HH, NB, GG);
    sample_kernel<<<gridB, 256, 0, stream>>>(in_last, coord_ws, out);
}

// Round 5
// 294.498 us; speedup vs baseline: 1.1204x; 1.1204x over previous
//
#include <hip/hip_runtime.h>
#include <hip/hip_bf16.h>
#include <math.h>

#define NB 8
#define CC 512
#define HH 64
#define WW 64
#define GG 16
#define GCH 32
#define OO 32                      // 2*G offset rows
#define NGHW (NB * GG * HH * WW)   // 524288 elements per coord buffer
#define NPX  (NB * HH * WW)        // 32768 pixels

// ws layout: [0, 4 MiB) px/py coords ; [4 MiB, 36 MiB) x1 bf16 [NPX][CC]

__device__ __forceinline__ float gelu_exact(float x) {
    return 0.5f * x * (1.0f + erff(x * 0.70710678118654752f));
}

__device__ __forceinline__ unsigned pack_bf2(float a, float b) {
    __hip_bfloat162 t = __float22bfloat162_rn(make_float2(a, b));
    return *(unsigned*)&t;
}

// ============================================================================
// Kernel 1: dwconv3x3 + LayerNorm + GELU -> x1 (bf16, pixel-major [NPX][CC]).
// grid (HH, NB), block 512; thread = 4 w x 16 ch. Registers die at the store
// (round-4's Phase D forced 64 live VGPRs across the whole kernel -> 4
// waves/SIMD and 73% stall; here the tail is a plain coalesced store).
// ============================================================================
__global__ __launch_bounds__(512, 2)
void conv_ln_gelu_kernel(const float* __restrict__ in_first,
                         const float* __restrict__ dw_w,
                         const float* __restrict__ dw_b,
                         const float* __restrict__ ln_g,
                         const float* __restrict__ ln_b,
                         __hip_bfloat16* __restrict__ x1)
{
    const int h   = blockIdx.x;
    const int n   = blockIdx.y;
    const int tid = threadIdx.x;
    const int wq   = tid & 15;
    const int cgrp = tid >> 4;
    const int wb = wq * 4;
    const int c0 = cgrp * 16;

    __shared__ float redS [64 * 33];
    __shared__ float redS2[64 * 33];
    __shared__ float meanArr[64];
    __shared__ float rstdArr[64];

    float xv[4][16];                 // fully-unrolled accesses only (no scratch!)
    float sw [4] = {0.f, 0.f, 0.f, 0.f};
    float sw2[4] = {0.f, 0.f, 0.f, 0.f};

    // ---------- depthwise 3x3 conv + bias (halo via shfl) ----------
    #pragma unroll
    for (int i = 0; i < 16; ++i) {
        const int c = c0 + i;
        float w9[9];
        #pragma unroll
        for (int k = 0; k < 9; ++k) w9[k] = dw_w[c * 9 + k];
        const float b = dw_b[c];
        float a0 = b, a1 = b, a2 = b, a3 = b;
        #pragma unroll
        for (int r = 0; r < 3; ++r) {
            const int y = h + r - 1;
            if (y < 0 || y >= HH) continue;
            const float* rowp = in_first + ((n * CC + c) * HH + y) * WW;
            const float4 m = *(const float4*)(rowp + wb);
            float left  = __shfl_up(m.w, 1);
            float right = __shfl_down(m.x, 1);
            if (wq == 0)  left  = 0.0f;
            if (wq == 15) right = 0.0f;
            const float k0 = w9[r * 3 + 0], k1 = w9[r * 3 + 1], k2 = w9[r * 3 + 2];
            a0 += k0 * left + k1 * m.x + k2 * m.y;
            a1 += k0 * m.x  + k1 * m.y + k2 * m.z;
            a2 += k0 * m.y  + k1 * m.z + k2 * m.w;
            a3 += k0 * m.z  + k1 * m.w + k2 * right;
        }
        xv[0][i] = a0; xv[1][i] = a1; xv[2][i] = a2; xv[3][i] = a3;
        sw[0] += a0; sw2[0] += a0 * a0;
        sw[1] += a1; sw2[1] += a1 * a1;
        sw[2] += a2; sw2[2] += a2 * a2;
        sw[3] += a3; sw2[3] += a3 * a3;
    }

    // ---------- LayerNorm stats over C per pixel ----------
    #pragma unroll
    for (int j = 0; j < 4; ++j) {
        redS [(wb + j) * 33 + cgrp] = sw[j];
        redS2[(wb + j) * 33 + cgrp] = sw2[j];
    }
    __syncthreads();
    if (tid < 64) {
        const int w = tid;
        float s = 0.f, s2 = 0.f;
        for (int k = 0; k < 32; ++k) {
            s  += redS [w * 33 + k];
            s2 += redS2[w * 33 + k];
        }
        const float mu  = s * (1.0f / 512.0f);
        const float var = s2 * (1.0f / 512.0f) - mu * mu;
        meanArr[w] = mu;
        rstdArr[w] = rsqrtf(var + 1e-6f);
    }
    __syncthreads();

    // ---------- LN affine + exact GELU + bf16 pack + store ----------
    float mu_[4], rs_[4];
    #pragma unroll
    for (int j = 0; j < 4; ++j) { mu_[j] = meanArr[wb + j]; rs_[j] = rstdArr[wb + j]; }
    #pragma unroll
    for (int i = 0; i < 16; ++i) {
        const int c = c0 + i;
        const float lg = ln_g[c];
        const float lb = ln_b[c];
        #pragma unroll
        for (int j = 0; j < 4; ++j) {
            const float v = (xv[j][i] - mu_[j]) * rs_[j] * lg + lb;
            xv[j][i] = gelu_exact(v);
        }
    }
    const int rowbase = (n * HH + h) * WW;
    #pragma unroll
    for (int j = 0; j < 4; ++j) {
        unsigned up[8];
        #pragma unroll
        for (int t = 0; t < 8; ++t) up[t] = pack_bf2(xv[j][2 * t], xv[j][2 * t + 1]);
        uint4* dst = (uint4*)(x1 + ((size_t)(rowbase + wb + j) * CC + c0));
        dst[0] = make_uint4(up[0], up[1], up[2], up[3]);
        dst[1] = make_uint4(up[4], up[5], up[6], up[7]);
    }
}

// ============================================================================
// Kernel 2: offset projection as MFMA GEMM [NPX x CC] x [CC x OO] -> coords.
// block 256 = 4 waves; each wave owns one 16(px) x 32(o) tile, K=512.
// A-frag: x1 row-major, 16 B loads.  B-frag: off_w[o][k] fp32 -> bf16 inline.
// C/D layout (verified m89/m91): col = lane&15, row = (lane>>4)*4 + reg.
// ============================================================================
typedef __attribute__((ext_vector_type(8))) short bf16x8;
typedef __attribute__((ext_vector_type(4))) float f32x4;

__global__ __launch_bounds__(256)
void offmat_kernel(const __hip_bfloat16* __restrict__ x1,
                   const float* __restrict__ off_w,
                   const float* __restrict__ off_b,
                   float* __restrict__ coords)
{
    const int tid  = threadIdx.x;
    const int wave = tid >> 6;
    const int lane = tid & 63;
    const int m0   = (blockIdx.x * 4 + wave) * 16;
    const int ml   = lane & 15;
    const int quad = lane >> 4;

    f32x4 acc0 = {0.f, 0.f, 0.f, 0.f};
    f32x4 acc1 = {0.f, 0.f, 0.f, 0.f};

    const short* arow  = (const short*)x1 + (size_t)(m0 + ml) * CC + quad * 8;
    const float* b0row = off_w + (size_t)ml * CC + quad * 8;          // o = ml
    const float* b1row = off_w + (size_t)(ml + 16) * CC + quad * 8;   // o = ml+16

    for (int k = 0; k < CC; k += 32) {
        const bf16x8 af = *(const bf16x8*)(arow + k);

        const float4 p0 = *(const float4*)(b0row + k);
        const float4 q0 = *(const float4*)(b0row + k + 4);
        union { bf16x8 v; unsigned u[4]; } b0;
        b0.u[0] = pack_bf2(p0.x, p0.y); b0.u[1] = pack_bf2(p0.z, p0.w);
        b0.u[2] = pack_bf2(q0.x, q0.y); b0.u[3] = pack_bf2(q0.z, q0.w);
        acc0 = __builtin_amdgcn_mfma_f32_16x16x32_bf16(af, b0.v, acc0, 0, 0, 0);

        const float4 p1 = *(const float4*)(b1row + k);
        const float4 q1 = *(const float4*)(b1row + k + 4);
        union { bf16x8 v; unsigned u[4]; } b1;
        b1.u[0] = pack_bf2(p1.x, p1.y); b1.u[1] = pack_bf2(p1.z, p1.w);
        b1.u[2] = pack_bf2(q1.x, q1.y); b1.u[3] = pack_bf2(q1.z, q1.w);
        acc1 = __builtin_amdgcn_mfma_f32_16x16x32_bf16(af, b1.v, acc1, 0, 0, 0);
    }

    // epilogue: D[m_local][n_local]; n_local = ml, m_local = quad*4 + r
    const int   o0  = ml;        // parity of o0 == parity of o1
    const int   o1  = ml + 16;
    const float ob0 = off_b[o0];
    const float ob1 = off_b[o1];
    const int   par = o0 & 1;
    const int   g0  = o0 >> 1;
    const int   g1  = o1 >> 1;

    #pragma unroll
    for (int r = 0; r < 4; ++r) {
        const int m  = m0 + quad * 4 + r;
        const int w  = m & 63;
        const int hh = (m >> 6) & 63;
        const int nn = m >> 12;
        const float base = par ? (float)hh : (float)w;
        coords[(size_t)par * NGHW + (((size_t)nn * GG + g0) * HH + hh) * WW + w]
            = base + acc0[r] + ob0;
        coords[(size_t)par * NGHW + (((size_t)nn * GG + g1) * HH + hh) * WW + w]
            = base + acc1[r] + ob1;
    }
}

// ============================================================================
// Kernel 3: bilinear gather + LDS transpose + coalesced NCHW store.
// grid (HH, NB, GG), block 256.
// ============================================================================
__global__ __launch_bounds__(256)
void sample_kernel(const float* __restrict__ in_last,
                   const float* __restrict__ coord_ws,
                   float* __restrict__ out)
{
    const int h   = blockIdx.x;
    const int n   = blockIdx.y;
    const int g   = blockIdx.z;
    const int tid = threadIdx.x;

    __shared__ float pxs[64];
    __shared__ float pys[64];
    __shared__ float smem[64 * 33];

    if (tid < 128) {
        const int w = tid & 63;
        const size_t cidx = (((size_t)n * GG + g) * HH + h) * WW + w;
        if (tid < 64) pxs[w] = coord_ws[cidx];
        else          pys[w] = coord_ws[cidx + NGHW];
    }
    __syncthreads();

    const int c4    = tid & 7;
    const int wslot = tid >> 3;
    const float* base = in_last + (size_t)n * HH * WW * CC + g * GCH + c4 * 4;

    #pragma unroll
    for (int pass = 0; pass < 2; ++pass) {
        const int w = wslot + pass * 32;
        const float px = pxs[w];
        const float py = pys[w];
        const float x0f = floorf(px), y0f = floorf(py);
        const float fx = px - x0f, fy = py - y0f;
        const int x0 = (int)x0f, y0 = (int)y0f;

        float4 acc = make_float4(0.f, 0.f, 0.f, 0.f);
        #pragma unroll
        for (int t = 0; t < 4; ++t) {
            const int xi = x0 + (t & 1);
            const int yi = y0 + (t >> 1);
            const float wt = ((t & 1) ? fx : 1.0f - fx) * ((t >> 1) ? fy : 1.0f - fy);
            if (xi >= 0 && xi < WW && yi >= 0 && yi < HH) {
                const float4 v = *(const float4*)(base + ((size_t)yi * WW + xi) * CC);
                acc.x += wt * v.x;
                acc.y += wt * v.y;
                acc.z += wt * v.z;
                acc.w += wt * v.w;
            }
        }
        float* sp = smem + w * 33 + c4 * 4;
        sp[0] = acc.x; sp[1] = acc.y; sp[2] = acc.z; sp[3] = acc.w;
    }
    __syncthreads();

    const int w  = tid & 63;
    const int cb = tid >> 6;
    float* op = out + (((size_t)n * CC + g * GCH) * HH + h) * WW + w;
    #pragma unroll
    for (int pass = 0; pass < 8; ++pass) {
        const int c = pass * 4 + cb;
        op[(size_t)c * (HH * WW)] = smem[w * 33 + c];
    }
}

extern "C" void kernel_launch(void* const* d_in, const int* in_sizes, int n_in,
                              void* d_out, int out_size, void* d_ws, size_t ws_size,
                              hipStream_t stream) {
    const float* in_first = (const float*)d_in[0];
    const float* in_last  = (const float*)d_in[1];
    const float* dw_w     = (const float*)d_in[2];
    const float* dw_b     = (const float*)d_in[3];
    const float* ln_g     = (const float*)d_in[4];
    const float* ln_b     = (const float*)d_in[5];
    const float* off_w    = (const float*)d_in[6];
    const float* off_b    = (const float*)d_in[7];
    float* out = (float*)d_out;

    float*          coord_ws = (float*)d_ws;                         // 4 MiB
    __hip_bfloat16* x1       = (__hip_bfloat16*)((char*)d_ws + (size_t)4 * 1024 * 1024); // 32 MiB

    dim3 gridA(HH, NB);
    conv_ln_gelu_kernel<<<gridA, 512, 0, stream>>>(in_first, dw_w, dw_b, ln_g, ln_b, x1);

    offmat_kernel<<<NPX / 64, 256, 0, stream>>>(x1, off_w, off_b, coord_ws);

    dim3 gridB(HH, NB, GG);
    sample_kernel<<<gridB, 256, 0, stream>>>(in_last, coord_ws, out);
}